// Round 1
// baseline (329.227 us; speedup 1.0000x reference)
//
#include <hip/hip_runtime.h>
#include <math.h>

// Problem constants
#define NTHREADS 256
#define TROWS 32            // rows (tokens) per block
#define TOKN 13824          // 24*24*24
#define MASKN 10368         // 0.75 * TOKN
#define UNMASKN 3456        // TOKN - MASKN
#define EMB 768
#define NPOS 24
#define NBATCH 4
#define ABLOCKS (TOKN / TROWS)    // 432 blocks for unmask rows (4 batches * 3456 rows)
#define BBLOCKS (MASKN / TROWS)   // 324 blocks for mask rows (computed once, stored x4)

__global__ __launch_bounds__(NTHREADS) void fused_embed_ln(
    const float* __restrict__ x, const float* __restrict__ W,
    const float* __restrict__ pb, const float* __restrict__ mt,
    const float* __restrict__ gmm, const float* __restrict__ bta,
    const int* __restrict__ perm, float* __restrict__ out)
{
  __shared__ __align__(16) float tab[NPOS * 256];    // 24 KB sincos table
  __shared__ __align__(16) float patch[TROWS * 64];  // 8 KB staged patch rows
  __shared__ float wred[TROWS][4][2];
  __shared__ float rowstat[TROWS][2];
  __shared__ int tok[TROWS];

  const int tid = threadIdx.x;
  const int blk = blockIdx.x;
  const bool isA = blk < ABLOCKS;

  // --- token indices for this block's rows ---
  if (tid < TROWS) {
    int r;
    if (isA) {
      int row0 = blk * TROWS;            // global unmask row in [0, 13824)
      int u = row0 % UNMASKN + tid;      // 3456 % 32 == 0 -> block stays in one batch
      r = perm[MASKN + u];               // unmask_idx[u]
    } else {
      int m0 = (blk - ABLOCKS) * TROWS;
      r = perm[m0 + tid];                // mask_idx[m]
    }
    tok[tid] = r;
  }

  // --- positional-encoding table: tab[pos*256 + e] ---
  // inv_freq[j] = 10000^(-j/128) = 2^(-j * log2(10000)/128)
  const float c0 = 13.287712379549449f / 128.0f;
  for (int i = tid; i < NPOS * 256; i += NTHREADS) {
    int pos = i >> 8, e = i & 255, j = e >> 1;
    float s = (float)pos * exp2f(-(float)j * c0);
    tab[i] = (e & 1) ? cosf(s) : sinf(s);
  }
  __syncthreads();

  // --- stage 32 patch rows (64 floats each) into LDS ---
  if (isA) {
    int b = (blk * TROWS) / UNMASKN;
    for (int i = tid; i < TROWS * 16; i += NTHREADS) {
      int t = i >> 4, seg = i & 15;        // seg = ph*4 + pw; float4 covers pd 0..3
      int token = tok[t];
      int h = token / 576; int rem = token - h * 576;
      int w = rem / 24;    int d = rem - w * 24;
      int ph = seg >> 2, pw = seg & 3;
      const float4* src = (const float4*)(x +
          ((((long)b * 96 + h * 4 + ph) * 96 + (w * 4 + pw)) * 96 + d * 4));
      ((float4*)patch)[i] = *src;
    }
  } else {
    int m0 = (blk - ABLOCKS) * TROWS;
    const float4* src = (const float4*)(mt + (long)m0 * 64);
    for (int i = tid; i < TROWS * 16; i += NTHREADS)
      ((float4*)patch)[i] = src[i];
  }
  __syncthreads();

  // --- GEMM: each thread accumulates columns {tid, tid+256, tid+512} for 32 rows ---
  float a0[TROWS], a1[TROWS], a2[TROWS];
  #pragma unroll
  for (int t = 0; t < TROWS; ++t) { a0[t] = 0.f; a1[t] = 0.f; a2[t] = 0.f; }

  for (int k4 = 0; k4 < 16; ++k4) {
    const float* wp = W + k4 * 4 * EMB + tid;
    float w00 = wp[0],       w01 = wp[256],         w02 = wp[512];
    float w10 = wp[EMB],     w11 = wp[EMB + 256],   w12 = wp[EMB + 512];
    float w20 = wp[2*EMB],   w21 = wp[2*EMB + 256], w22 = wp[2*EMB + 512];
    float w30 = wp[3*EMB],   w31 = wp[3*EMB + 256], w32 = wp[3*EMB + 512];
    #pragma unroll
    for (int t = 0; t < TROWS; ++t) {
      float4 p = *((const float4*)(patch + t * 64 + k4 * 4)); // wave-uniform broadcast
      a0[t] += p.x * w00; a1[t] += p.x * w01; a2[t] += p.x * w02;
      a0[t] += p.y * w10; a1[t] += p.y * w11; a2[t] += p.y * w12;
      a0[t] += p.z * w20; a1[t] += p.z * w21; a2[t] += p.z * w22;
      a0[t] += p.w * w30; a1[t] += p.w * w31; a2[t] += p.w * w32;
    }
  }

  const float pb0 = pb[tid], pb1 = pb[tid + 256], pb2 = pb[tid + 512];
  const float g0 = gmm[tid], g1 = gmm[tid + 256], g2 = gmm[tid + 512];
  const float b0 = bta[tid], b1 = bta[tid + 256], b2 = bta[tid + 512];
  const int wv = tid >> 6, ln = tid & 63;

  // --- LN reductions: per-row sum / sumsq (wave shuffle, then cross-wave in LDS) ---
  #pragma unroll
  for (int t = 0; t < TROWS; ++t) {
    int token = tok[t];
    int h = token / 576; int rem = token - h * 576;
    int w = rem / 24;    int d = rem - w * 24;
    float v0 = a0[t] + pb0 + tab[h * 256 + tid];
    float v1 = a1[t] + pb1 + tab[w * 256 + tid];
    float v2 = a2[t] + pb2 + tab[d * 256 + tid];
    float s = v0 + v1 + v2;
    float q = v0 * v0 + v1 * v1 + v2 * v2;
    #pragma unroll
    for (int off = 32; off > 0; off >>= 1) {
      s += __shfl_down(s, off, 64);
      q += __shfl_down(q, off, 64);
    }
    if (ln == 0) { wred[t][wv][0] = s; wred[t][wv][1] = q; }
  }
  __syncthreads();
  if (tid < TROWS) {
    float s = wred[tid][0][0] + wred[tid][1][0] + wred[tid][2][0] + wred[tid][3][0];
    float q = wred[tid][0][1] + wred[tid][1][1] + wred[tid][2][1] + wred[tid][3][1];
    float mean = s * (1.0f / 768.0f);
    float var = q * (1.0f / 768.0f) - mean * mean;   // biased, matches jnp.var
    rowstat[tid][0] = mean;
    rowstat[tid][1] = 1.0f / sqrtf(var + 0.001f);    // LN_EPS
  }
  __syncthreads();

  // --- normalize + store (mask rows broadcast to all 4 batches) ---
  #pragma unroll
  for (int t = 0; t < TROWS; ++t) {
    int token = tok[t];
    int h = token / 576; int rem = token - h * 576;
    int w = rem / 24;    int d = rem - w * 24;
    float mean = rowstat[t][0], rstd = rowstat[t][1];
    float o0 = (a0[t] + pb0 + tab[h * 256 + tid] - mean) * rstd * g0 + b0;
    float o1 = (a1[t] + pb1 + tab[w * 256 + tid] - mean) * rstd * g1 + b1;
    float o2 = (a2[t] + pb2 + tab[d * 256 + tid] - mean) * rstd * g2 + b2;
    if (isA) {
      int row0 = blk * TROWS;
      int b = row0 / UNMASKN;
      int u = row0 % UNMASKN + t;
      float* o = out + ((long)b * TOKN + u) * EMB;
      o[tid] = o0; o[tid + 256] = o1; o[tid + 512] = o2;
    } else {
      int m = (blk - ABLOCKS) * TROWS + t;
      #pragma unroll
      for (int bb = 0; bb < NBATCH; ++bb) {
        float* o = out + ((long)bb * TOKN + UNMASKN + m) * EMB;
        o[tid] = o0; o[tid + 256] = o1; o[tid + 512] = o2;
      }
    }
  }
}

__global__ void mask_idx_kernel(const int* __restrict__ perm, float* __restrict__ out2) {
  int i = blockIdx.x * NTHREADS + threadIdx.x;
  if (i < MASKN) out2[i] = (float)perm[i];
}

extern "C" void kernel_launch(void* const* d_in, const int* in_sizes, int n_in,
                              void* d_out, int out_size, void* d_ws, size_t ws_size,
                              hipStream_t stream) {
  const float* x    = (const float*)d_in[0];
  const float* W    = (const float*)d_in[1];
  const float* pb   = (const float*)d_in[2];
  const float* mt   = (const float*)d_in[3];
  const float* gmm  = (const float*)d_in[4];
  const float* bta  = (const float*)d_in[5];
  const int*   perm = (const int*)d_in[6];
  float* out = (float*)d_out;
  float* out_idx = out + (long)NBATCH * TOKN * EMB;   // 42,467,328

  fused_embed_ln<<<ABLOCKS + BBLOCKS, NTHREADS, 0, stream>>>(
      x, W, pb, mt, gmm, bta, perm, out);
  mask_idx_kernel<<<(MASKN + NTHREADS - 1) / NTHREADS, NTHREADS, 0, stream>>>(
      perm, out_idx);
}